// Round 1
// baseline (1095.192 us; speedup 1.0000x reference)
//
#include <hip/hip_runtime.h>
#include <math.h>

#define NE 150000

// type ids: SB=0 PQ=1 PV=2 NB=3
__constant__ int c_stype[15] = {2,0,0,2,3,1,0,1,3,1,2,3,2,1,3};
__constant__ int c_dtype[15] = {0,1,3,1,1,3,2,0,0,2,3,2,2,1,3};
__constant__ int c_slot[15]  = {0,0,0,1,2,1,0,1,2,1,2,2,3,3,3};
__constant__ int c_N[4]      = {4000,30000,15000,12000};
__constant__ int c_xoff[4]   = {0,4000,34000,49000};
__constant__ int c_cnt[4]    = {3,4,4,4};
__constant__ int c_aggoff[4] = {0,24000,264000,384000};
__constant__ int c_outoff[4] = {0,48000,528000,768000};
__constant__ int c_aggrows[4]= {24000,240000,120000,96000};

__device__ __forceinline__ float eluf(float x){ return x > 0.0f ? x : expm1f(x); }
__device__ __forceinline__ unsigned encf(float f){ unsigned u=__float_as_uint(f); return (u&0x80000000u)? ~u : (u|0x80000000u); }
__device__ __forceinline__ float decf(unsigned u){ return __uint_as_float((u&0x80000000u)? (u^0x80000000u) : ~u); }

// ---- build x = concat(x_nt, c_nt) for all 61000 nodes ----
__global__ __launch_bounds__(256) void k_build_x(
    const float* __restrict__ xSB, const float* __restrict__ cSB,
    const float* __restrict__ xPQ, const float* __restrict__ cPQ,
    const float* __restrict__ xPV, const float* __restrict__ cPV,
    const float* __restrict__ xNB, const float* __restrict__ cNB,
    float* __restrict__ xall){
  int n = blockIdx.x*256 + threadIdx.x;
  if (n >= 61000) return;
  const float *xp, *cp; int local;
  if (n < 4000)      { xp=xSB; cp=cSB; local=n; }
  else if (n < 34000){ xp=xPQ; cp=cPQ; local=n-4000; }
  else if (n < 49000){ xp=xPV; cp=cPV; local=n-34000; }
  else               { xp=xNB; cp=cNB; local=n-49000; }
  float4 a = ((const float4*)xp)[local];
  float4 b = ((const float4*)cp)[local];
  ((float4*)xall)[n*2+0] = a;
  ((float4*)xall)[n*2+1] = b;
}

// ---- derive per-conv small params (160 floats per conv) ----
// layout: [0:64] A=Wq*Wk^T, [64]u=Wq*bk, [72]wkbq=Wk*bq, [80]Wq*We0, [88]Wq*We1,
// [96]Wq*be, [104]wv0, [112]wv1, [120]ws0, [128]ws1, [136]c0, [137]bq*We0,
// [138]bq*We1, [139]bq*be, [140]we00,[141]we01,[142]we10,[143]we11,
// [144]bv0,[145]bv1,[146]be0,[147]be1,[148]bs0,[149]bs1
__global__ __launch_bounds__(64) void k_params(
    const float* __restrict__ Wq, const float* __restrict__ bq,
    const float* __restrict__ Wk, const float* __restrict__ bk,
    const float* __restrict__ Wv, const float* __restrict__ bv,
    const float* __restrict__ We, const float* __restrict__ be,
    const float* __restrict__ Ws, const float* __restrict__ bs,
    float* __restrict__ par){
  const int c = blockIdx.x, tid = threadIdx.x;
  const float* wq = Wq + (size_t)c*1024;
  const float* wk = Wk + (size_t)c*1024;
  const float* wv = Wv + (size_t)c*1024;
  const float* ws = Ws + (size_t)c*1024;
  const float* we = We + (size_t)c*256;
  const float* vbq = bq + (size_t)c*128;
  const float* vbk = bk + (size_t)c*128;
  const float* vbv = bv + (size_t)c*128;
  const float* vbe = be + (size_t)c*128;
  const float* vbs = bs + (size_t)c*128;
  float* P = par + (size_t)c*160;
  { int fd = tid>>3, fs = tid&7; float s=0.f;
    for (int h=0;h<128;h++) s = fmaf(wq[fd*128+h], wk[fs*128+h], s);
    P[tid]=s; }
  const int grp = tid>>3, f = tid&7;
  if (grp==0){ float s=0.f; for(int h=0;h<128;h++) s=fmaf(wq[f*128+h],vbk[h],s); P[64+f]=s; }
  else if (grp==1){ float s=0.f; for(int h=0;h<128;h++) s=fmaf(wk[f*128+h],vbq[h],s); P[72+f]=s; }
  else if (grp==2){ float s=0.f; for(int h=0;h<128;h++) s=fmaf(wq[f*128+h],we[h],s); P[80+f]=s; }
  else if (grp==3){ float s=0.f; for(int h=0;h<128;h++) s=fmaf(wq[f*128+h],we[128+h],s); P[88+f]=s; }
  else if (grp==4){ float s=0.f; for(int h=0;h<128;h++) s=fmaf(wq[f*128+h],vbe[h],s); P[96+f]=s; }
  else if (grp==5){ float s0=0.f,s1=0.f; for(int h=0;h<64;h++){s0+=wv[f*128+h]; s1+=wv[f*128+64+h];} P[104+f]=s0; P[112+f]=s1; }
  else if (grp==6){ float s0=0.f,s1=0.f; for(int h=0;h<64;h++){s0+=ws[f*128+h]; s1+=ws[f*128+64+h];} P[120+f]=s0; P[128+f]=s1; }
  else {
    if (f==0){ float s=0.f; for(int h=0;h<128;h++) s=fmaf(vbq[h],vbk[h],s); P[136]=s;
               float a=0.f,b=0.f; for(int h=0;h<64;h++){a+=vbs[h]; b+=vbs[64+h];} P[148]=a; P[149]=b; }
    else if (f==1){ float s=0.f; for(int h=0;h<128;h++) s=fmaf(vbq[h],we[h],s); P[137]=s; }
    else if (f==2){ float s=0.f; for(int h=0;h<128;h++) s=fmaf(vbq[h],we[128+h],s); P[138]=s; }
    else if (f==3){ float s=0.f; for(int h=0;h<128;h++) s=fmaf(vbq[h],vbe[h],s); P[139]=s; }
    else if (f==4){ float a=0.f,b=0.f; for(int h=0;h<64;h++){a+=we[h]; b+=we[64+h];} P[140]=a; P[141]=b; }
    else if (f==5){ float a=0.f,b=0.f; for(int h=0;h<64;h++){a+=we[128+h]; b+=we[192+h];} P[142]=a; P[143]=b; }
    else if (f==6){ float a=0.f,b=0.f; for(int h=0;h<64;h++){a+=vbv[h]; b+=vbv[64+h];} P[144]=a; P[145]=b; }
    else          { float a=0.f,b=0.f; for(int h=0;h<64;h++){a+=vbe[h]; b+=vbe[64+h];} P[146]=a; P[147]=b; }
  }
}

// ---- edge pass: logit via bilinear form, exp, atomics into den/num0/num1 ----
__global__ __launch_bounds__(256) void k_edges(
    const int* __restrict__ eidx, const float* __restrict__ eattr,
    const float* __restrict__ xall, const float* __restrict__ par,
    float* __restrict__ den, float* __restrict__ num0, float* __restrict__ num1){
  const int c = blockIdx.y, t = c % 15, i = c / 15;
  __shared__ float sP[160];
  if (threadIdx.x < 160) sP[threadIdx.x] = par[(size_t)c*160 + threadIdx.x];
  __syncthreads();
  const int e = blockIdx.x*256 + threadIdx.x;
  if (e >= NE) return;
  const int st = c_stype[t], dt = c_dtype[t];
  const int src = eidx[(t*2+0)*NE + e];
  const int dst = eidx[(t*2+1)*NE + e];
  const float2 ea = ((const float2*)eattr)[(size_t)t*NE + e];
  const float4* xsp = (const float4*)(xall + (size_t)(c_xoff[st] + src)*8);
  const float4* xdp = (const float4*)(xall + (size_t)(c_xoff[dt] + dst)*8);
  float4 a0 = xsp[0], a1 = xsp[1], b0 = xdp[0], b1 = xdp[1];
  float xs[8] = {a0.x,a0.y,a0.z,a0.w,a1.x,a1.y,a1.z,a1.w};
  float xd[8] = {b0.x,b0.y,b0.z,b0.w,b1.x,b1.y,b1.z,b1.w};
  float acc = sP[136];
  #pragma unroll
  for (int fd=0; fd<8; fd++){
    float tmp = 0.f;
    #pragma unroll
    for (int fs=0; fs<8; fs++) tmp = fmaf(sP[fd*8+fs], xs[fs], tmp);
    acc = fmaf(xd[fd], tmp, acc);
  }
  float t0 = sP[137], t1 = sP[138], tb = sP[139];
  float v0 = fmaf(ea.x, sP[140], fmaf(ea.y, sP[142], sP[144] + sP[146]));
  float v1 = fmaf(ea.x, sP[141], fmaf(ea.y, sP[143], sP[145] + sP[147]));
  #pragma unroll
  for (int f=0; f<8; f++){
    acc = fmaf(xd[f], sP[64+f], acc);
    acc = fmaf(xs[f], sP[72+f], acc);
    t0  = fmaf(xd[f], sP[80+f], t0);
    t1  = fmaf(xd[f], sP[88+f], t1);
    tb  = fmaf(xd[f], sP[96+f], tb);
    v0  = fmaf(xs[f], sP[104+f], v0);
    v1  = fmaf(xs[f], sP[112+f], v1);
  }
  acc += fmaf(ea.x, t0, fmaf(ea.y, t1, tb));
  const float pe = expf(acc * 0.08838834764831845f);  // * 1/sqrt(128)
  const int base = c_aggoff[dt] + (i*c_cnt[dt] + c_slot[t])*c_N[dt] + dst;
  atomicAdd(den  + base, pe);
  atomicAdd(num0 + base, pe*v0);
  atomicAdd(num1 + base, pe*v1);
}

// ---- per-(conv,node): g = num/den + skip half-sums ----
__global__ __launch_bounds__(256) void k_gfin(
    const float* __restrict__ xall, const float* __restrict__ par,
    const float* __restrict__ den, const float* __restrict__ num0, const float* __restrict__ num1,
    float* __restrict__ g){
  const int c = blockIdx.y, t = c % 15, i = c / 15;
  const int dt = c_dtype[t];
  const int n = blockIdx.x*256 + threadIdx.x;
  if (n >= c_N[dt]) return;
  const float* P = par + (size_t)c*160;
  const int base = c_aggoff[dt] + (i*c_cnt[dt] + c_slot[t])*c_N[dt] + n;
  const float4* xdp = (const float4*)(xall + (size_t)(c_xoff[dt]+n)*8);
  float4 b0 = xdp[0], b1 = xdp[1];
  float xd[8] = {b0.x,b0.y,b0.z,b0.w,b1.x,b1.y,b1.z,b1.w};
  const float inv = 1.0f/(den[base] + 1e-16f);
  float s0 = fmaf(num0[base], inv, P[148]);
  float s1 = fmaf(num1[base], inv, P[149]);
  #pragma unroll
  for (int f=0; f<8; f++){
    s0 = fmaf(xd[f], P[120+f], s0);
    s1 = fmaf(xd[f], P[128+f], s1);
  }
  g[(size_t)base*2+0] = s0;
  g[(size_t)base*2+1] = s1;
}

// ---- global min/max of z = g @ W_lin + b_lin (elu is monotone) ----
__global__ __launch_bounds__(256) void k_minmax(
    const float* __restrict__ g, const float* __restrict__ Wl, const float* __restrict__ bl,
    unsigned* __restrict__ mm){
  const int r = blockIdx.x*256 + threadIdx.x;
  float lmin = 3.4e38f, lmax = -3.4e38f;
  if (r < 480000){
    const float g0 = g[(size_t)r*2+0], g1 = g[(size_t)r*2+1];
    #pragma unroll
    for (int h=0; h<64; h++){
      float z = fmaf(g0, Wl[h], fmaf(g1, Wl[64+h], bl[h]));
      lmin = fminf(lmin, z); lmax = fmaxf(lmax, z);
    }
  }
  #pragma unroll
  for (int m=32; m>=1; m>>=1){
    lmin = fminf(lmin, __shfl_xor(lmin, m));
    lmax = fmaxf(lmax, __shfl_xor(lmax, m));
  }
  __shared__ float smin[4], smax[4];
  const int w = threadIdx.x>>6;
  if ((threadIdx.x&63)==0){ smin[w]=lmin; smax[w]=lmax; }
  __syncthreads();
  if (threadIdx.x==0){
    float mn = fminf(fminf(smin[0],smin[1]), fminf(smin[2],smin[3]));
    float mx = fmaxf(fmaxf(smax[0],smax[1]), fmaxf(smax[2],smax[3]));
    atomicMin(&mm[0], encf(mn));
    atomicMax(&mm[1], encf(mx));
  }
}

// ---- final: per row -> z -> elu -> norm -> @W_fc[j] -> elu -> halfsum -> @W_lin2 -> elu
// wave-per-row, lane = output channel; duplicate row write (layer copies identical)
__global__ __launch_bounds__(256) void k_final(
    const float* __restrict__ g, const unsigned* __restrict__ mm,
    const float* __restrict__ Wl, const float* __restrict__ bl,
    const float* __restrict__ Wfc, const float* __restrict__ bfc,
    const float* __restrict__ Wl2, const float* __restrict__ bl2,
    float* __restrict__ out){
  const int bid = blockIdx.x;
  int nt, bo;
  if (bid < 6000)       { nt=0; bo=0; }
  else if (bid < 66000) { nt=1; bo=6000; }
  else if (bid < 96000) { nt=2; bo=66000; }
  else                  { nt=3; bo=96000; }
  const int w = threadIdx.x>>6, lane = threadIdx.x&63;
  const int rl = (bid-bo)*4 + w;
  const int R = c_aggrows[nt];
  if (rl >= R) return;
  // hoisted weights (lane doubles as h in stage-1 and o in stage-2)
  const float wl0 = Wl[lane], wl1 = Wl[64+lane], blv = bl[lane];
  const float bfcv = bfc[nt*64+lane];
  const float wl20 = Wl2[lane], wl21 = Wl2[64+lane], bl2v = bl2[lane];
  float wfcr[64];
  const float* W = Wfc + (size_t)nt*4096;
  #pragma unroll
  for (int h=0; h<64; h++) wfcr[h] = W[h*64 + lane];
  const float zmin = decf(mm[0]), zmax = decf(mm[1]);
  const float rmin = 0.1f*eluf(zmin);
  const float rmax = 0.9f + 0.1f*eluf(zmax);
  const float s2 = 2.0f/(rmax - rmin + 1e-5f);
  const int idx = c_aggoff[nt] + rl;
  const float g0 = g[(size_t)idx*2+0], g1 = g[(size_t)idx*2+1];
  const float z = fmaf(g0, wl0, fmaf(g1, wl1, blv));
  const float a = eluf(z);
  const float nrm = fmaf(a - rmin, s2, -1.0f);
  float acc = bfcv;
  #pragma unroll
  for (int h=0; h<64; h++){
    float nh = __uint_as_float(__builtin_amdgcn_readlane(__float_as_uint(nrm), h));
    acc = fmaf(nh, wfcr[h], acc);
  }
  float b = eluf(acc);
  float s = b;
  s += __shfl_xor(s, 16);
  s += __shfl_xor(s, 8);
  s += __shfl_xor(s, 4);
  s += __shfl_xor(s, 2);
  s += __shfl_xor(s, 1);
  const float h0 = __uint_as_float(__builtin_amdgcn_readlane(__float_as_uint(s), 0));
  const float h1 = __uint_as_float(__builtin_amdgcn_readlane(__float_as_uint(s), 32));
  const float f = eluf(fmaf(h0, wl20, fmaf(h1, wl21, bl2v)));
  const size_t orow = (size_t)c_outoff[nt] + rl;
  out[orow*64 + lane] = f;
  out[(orow + (size_t)R)*64 + lane] = f;
}

extern "C" void kernel_launch(void* const* d_in, const int* in_sizes, int n_in,
                              void* d_out, int out_size, void* d_ws, size_t ws_size,
                              hipStream_t stream) {
  const float* xSB = (const float*)d_in[0];
  const float* cSB = (const float*)d_in[1];
  const float* xPQ = (const float*)d_in[2];
  const float* cPQ = (const float*)d_in[3];
  const float* xPV = (const float*)d_in[4];
  const float* cPV = (const float*)d_in[5];
  const float* xNB = (const float*)d_in[6];
  const float* cNB = (const float*)d_in[7];
  const int*   eidx = (const int*)d_in[8];
  const float* eattr= (const float*)d_in[9];
  const float* Wq = (const float*)d_in[10];
  const float* bq = (const float*)d_in[11];
  const float* Wk = (const float*)d_in[12];
  const float* bk = (const float*)d_in[13];
  const float* Wv = (const float*)d_in[14];
  const float* bv = (const float*)d_in[15];
  const float* We = (const float*)d_in[16];
  const float* be = (const float*)d_in[17];
  const float* Ws = (const float*)d_in[18];
  const float* bs = (const float*)d_in[19];
  const float* Wl = (const float*)d_in[20];
  const float* bl = (const float*)d_in[21];
  const float* Wfc= (const float*)d_in[22];
  const float* bfc= (const float*)d_in[23];
  const float* Wl2= (const float*)d_in[24];
  const float* bl2= (const float*)d_in[25];

  float* ws   = (float*)d_ws;
  float* xall = ws + 0;         // 488000
  float* par  = ws + 488000;    // 4800
  float* den  = ws + 492800;    // 480000
  float* num0 = ws + 972800;    // 480000
  float* num1 = ws + 1452800;   // 480000
  float* g    = ws + 1932800;   // 960000
  unsigned* mm = (unsigned*)(ws + 2892800); // 2

  hipMemsetAsync(den, 0, (size_t)3*480000*sizeof(float), stream);
  hipMemsetAsync(mm,   0xFF, 4, stream);  // encoded min identity
  hipMemsetAsync(mm+1, 0x00, 4, stream);  // encoded max identity

  k_build_x<<<(61000+255)/256, 256, 0, stream>>>(xSB,cSB,xPQ,cPQ,xPV,cPV,xNB,cNB, xall);
  k_params<<<30, 64, 0, stream>>>(Wq,bq,Wk,bk,Wv,bv,We,be,Ws,bs, par);
  dim3 ge((NE+255)/256, 30);
  k_edges<<<ge, 256, 0, stream>>>(eidx, eattr, xall, par, den, num0, num1);
  dim3 gg((30000+255)/256, 30);
  k_gfin<<<gg, 256, 0, stream>>>(xall, par, den, num0, num1, g);
  k_minmax<<<480000/256, 256, 0, stream>>>(g, Wl, bl, mm);
  k_final<<<120000, 256, 0, stream>>>(g, mm, Wl, bl, Wfc, bfc, Wl2, bl2, (float*)d_out);
}

// Round 2
// 615.017 us; speedup vs baseline: 1.7808x; 1.7808x over previous
//
#include <hip/hip_runtime.h>
#include <math.h>

#define NE 150000

// type ids: SB=0 PQ=1 PV=2 NB=3
__constant__ int c_stype[15] = {2,0,0,2,3,1,0,1,3,1,2,3,2,1,3};
__constant__ int c_dtype[15] = {0,1,3,1,1,3,2,0,0,2,3,2,2,1,3};
__constant__ int c_slot[15]  = {0,0,0,1,2,1,0,1,2,1,2,2,3,3,3};
__constant__ int c_N[4]      = {4000,30000,15000,12000};
__constant__ int c_xoff[4]   = {0,4000,34000,49000};
__constant__ int c_cnt[4]    = {3,4,4,4};
__constant__ int c_aggoff[4] = {0,24000,264000,384000};
__constant__ int c_outoff[4] = {0,48000,528000,768000};
__constant__ int c_aggrows[4]= {24000,240000,120000,96000};
// per-type CSR offsets into gstart (stride N+1 per type)
__constant__ int c_toff2[15] = {0,4001,34002,46003,76004,106005,118006,133007,137008,141009,156010,168011,183012,198013,228014};

__device__ __forceinline__ float eluf(float x){ return x > 0.0f ? x : expm1f(x); }
__device__ __forceinline__ unsigned encf(float f){ unsigned u=__float_as_uint(f); return (u&0x80000000u)? ~u : (u|0x80000000u); }
__device__ __forceinline__ float decf(unsigned u){ return __uint_as_float((u&0x80000000u)? (u^0x80000000u) : ~u); }

// ---- build x = concat(x_nt, c_nt) for all 61000 nodes ----
__global__ __launch_bounds__(256) void k_build_x(
    const float* __restrict__ xSB, const float* __restrict__ cSB,
    const float* __restrict__ xPQ, const float* __restrict__ cPQ,
    const float* __restrict__ xPV, const float* __restrict__ cPV,
    const float* __restrict__ xNB, const float* __restrict__ cNB,
    float* __restrict__ xall){
  int n = blockIdx.x*256 + threadIdx.x;
  if (n >= 61000) return;
  const float *xp, *cp; int local;
  if (n < 4000)      { xp=xSB; cp=cSB; local=n; }
  else if (n < 34000){ xp=xPQ; cp=cPQ; local=n-4000; }
  else if (n < 49000){ xp=xPV; cp=cPV; local=n-34000; }
  else               { xp=xNB; cp=cNB; local=n-49000; }
  float4 a = ((const float4*)xp)[local];
  float4 b = ((const float4*)cp)[local];
  ((float4*)xall)[n*2+0] = a;
  ((float4*)xall)[n*2+1] = b;
}

// ---- derive per-conv small params (160 floats per conv) ----
__global__ __launch_bounds__(64) void k_params(
    const float* __restrict__ Wq, const float* __restrict__ bq,
    const float* __restrict__ Wk, const float* __restrict__ bk,
    const float* __restrict__ Wv, const float* __restrict__ bv,
    const float* __restrict__ We, const float* __restrict__ be,
    const float* __restrict__ Ws, const float* __restrict__ bs,
    float* __restrict__ par){
  const int c = blockIdx.x, tid = threadIdx.x;
  const float* wq = Wq + (size_t)c*1024;
  const float* wk = Wk + (size_t)c*1024;
  const float* wv = Wv + (size_t)c*1024;
  const float* ws = Ws + (size_t)c*1024;
  const float* we = We + (size_t)c*256;
  const float* vbq = bq + (size_t)c*128;
  const float* vbk = bk + (size_t)c*128;
  const float* vbv = bv + (size_t)c*128;
  const float* vbe = be + (size_t)c*128;
  const float* vbs = bs + (size_t)c*128;
  float* P = par + (size_t)c*160;
  { int fd = tid>>3, fs = tid&7; float s=0.f;
    for (int h=0;h<128;h++) s = fmaf(wq[fd*128+h], wk[fs*128+h], s);
    P[tid]=s; }
  const int grp = tid>>3, f = tid&7;
  if (grp==0){ float s=0.f; for(int h=0;h<128;h++) s=fmaf(wq[f*128+h],vbk[h],s); P[64+f]=s; }
  else if (grp==1){ float s=0.f; for(int h=0;h<128;h++) s=fmaf(wk[f*128+h],vbq[h],s); P[72+f]=s; }
  else if (grp==2){ float s=0.f; for(int h=0;h<128;h++) s=fmaf(wq[f*128+h],we[h],s); P[80+f]=s; }
  else if (grp==3){ float s=0.f; for(int h=0;h<128;h++) s=fmaf(wq[f*128+h],we[128+h],s); P[88+f]=s; }
  else if (grp==4){ float s=0.f; for(int h=0;h<128;h++) s=fmaf(wq[f*128+h],vbe[h],s); P[96+f]=s; }
  else if (grp==5){ float s0=0.f,s1=0.f; for(int h=0;h<64;h++){s0+=wv[f*128+h]; s1+=wv[f*128+64+h];} P[104+f]=s0; P[112+f]=s1; }
  else if (grp==6){ float s0=0.f,s1=0.f; for(int h=0;h<64;h++){s0+=ws[f*128+h]; s1+=ws[f*128+64+h];} P[120+f]=s0; P[128+f]=s1; }
  else {
    if (f==0){ float s=0.f; for(int h=0;h<128;h++) s=fmaf(vbq[h],vbk[h],s); P[136]=s;
               float a=0.f,b=0.f; for(int h=0;h<64;h++){a+=vbs[h]; b+=vbs[64+h];} P[148]=a; P[149]=b; }
    else if (f==1){ float s=0.f; for(int h=0;h<128;h++) s=fmaf(vbq[h],we[h],s); P[137]=s; }
    else if (f==2){ float s=0.f; for(int h=0;h<128;h++) s=fmaf(vbq[h],we[128+h],s); P[138]=s; }
    else if (f==3){ float s=0.f; for(int h=0;h<128;h++) s=fmaf(vbq[h],vbe[h],s); P[139]=s; }
    else if (f==4){ float a=0.f,b=0.f; for(int h=0;h<64;h++){a+=we[h]; b+=we[64+h];} P[140]=a; P[141]=b; }
    else if (f==5){ float a=0.f,b=0.f; for(int h=0;h<64;h++){a+=we[128+h]; b+=we[192+h];} P[142]=a; P[143]=b; }
    else if (f==6){ float a=0.f,b=0.f; for(int h=0;h<64;h++){a+=vbv[h]; b+=vbv[64+h];} P[144]=a; P[145]=b; }
    else          { float a=0.f,b=0.f; for(int h=0;h<64;h++){a+=vbe[h]; b+=vbe[64+h];} P[146]=a; P[147]=b; }
  }
}

// ---- CSR build: one block per edge type, LDS counting sort (no global atomics) ----
__global__ __launch_bounds__(1024) void k_csr(const int* __restrict__ eidx,
                                              int* __restrict__ gstart,
                                              int* __restrict__ pool){
  const int t = blockIdx.x;
  const int N = c_N[c_dtype[t]];
  const int o = c_toff2[t];
  const int tid = threadIdx.x;
  __shared__ int cnt[30000];
  __shared__ int wtot[16];
  for (int k=tid; k<N; k+=1024) cnt[k]=0;
  __syncthreads();
  const int* __restrict__ dstp = eidx + (size_t)(t*2+1)*NE;
  for (int e=tid; e<NE; e+=1024) atomicAdd(&cnt[dstp[e]], 1);
  __syncthreads();
  // block-wide exclusive scan over cnt[0..N)
  const int K = (N+1023)>>10;
  const int b0 = tid*K;
  int s = 0;
  for (int j=0;j<K;j++){ int k=b0+j; if (k<N) s += cnt[k]; }
  const int lane = tid & 63, wid = tid >> 6;
  int v = s;
  #pragma unroll
  for (int off=1; off<64; off<<=1){ int u = __shfl_up(v, off); if (lane>=off) v += u; }
  if (lane==63) wtot[wid]=v;
  __syncthreads();
  if (tid==0){ int r=0; for (int k=0;k<16;k++){ int tmp=wtot[k]; wtot[k]=r; r+=tmp; } }
  __syncthreads();
  int run = wtot[wid] + (v - s);
  for (int j=0;j<K;j++){ int k=b0+j; if (k<N){ int c0=cnt[k]; cnt[k]=run; run += c0; } }
  __syncthreads();
  for (int k=tid; k<N; k+=1024) gstart[o+k]=cnt[k];
  if (tid==0) gstart[o+N]=NE;
  __syncthreads();
  for (int e=tid; e<NE; e+=1024){
    int d = dstp[e];
    int pos = atomicAdd(&cnt[d], 1);
    pool[(size_t)t*NE + pos] = e;
  }
}

// ---- gather: per (conv,node) walk CSR run; fuse softmax, skip (gfin) and minmax ----
__global__ __launch_bounds__(256) void k_gather(
    const int* __restrict__ eidx, const float* __restrict__ eattr,
    const int* __restrict__ gstart, const int* __restrict__ pool,
    const float* __restrict__ xall, const float* __restrict__ par,
    const float* __restrict__ Wl, const float* __restrict__ bl,
    float* __restrict__ g, unsigned* __restrict__ mm){
  const int c = blockIdx.y, t = c % 15, i = c / 15;
  const int dt = c_dtype[t], st = c_stype[t];
  const int N = c_N[dt];
  if (blockIdx.x*256 >= N) return;
  __shared__ float sP[160];
  __shared__ float wlb[192];
  __shared__ float smin[4], smax[4];
  const int tid = threadIdx.x;
  if (tid < 160) sP[tid] = par[(size_t)c*160 + tid];
  if (tid < 192) wlb[tid] = (tid<128)? Wl[tid] : bl[tid-128];
  __syncthreads();
  const int n = blockIdx.x*256 + tid;
  const bool valid = n < N;
  float lmin = 3.4e38f, lmax = -3.4e38f;
  if (valid){
    const float4* xdp = (const float4*)(xall + (size_t)(c_xoff[dt]+n)*8);
    float4 b0v = xdp[0], b1v = xdp[1];
    float xd[8] = {b0v.x,b0v.y,b0v.z,b0v.w,b1v.x,b1v.y,b1v.z,b1v.w};
    // per-node hoists
    float r2[8];
    #pragma unroll
    for (int fs=0; fs<8; fs++){
      float a = sP[72+fs];
      #pragma unroll
      for (int fd=0; fd<8; fd++) a = fmaf(xd[fd], sP[fd*8+fs], a);
      r2[fs]=a;
    }
    float t0=sP[137], t1=sP[138], tb=sP[139], u0=sP[136];
    #pragma unroll
    for (int f=0;f<8;f++){
      t0 = fmaf(xd[f], sP[80+f], t0);
      t1 = fmaf(xd[f], sP[88+f], t1);
      tb = fmaf(xd[f], sP[96+f], tb);
      u0 = fmaf(xd[f], sP[64+f], u0);
    }
    const float accd = u0 + tb;
    const int o = c_toff2[t];
    const int js = gstart[o+n], je = gstart[o+n+1];
    const int* __restrict__ srcp = eidx + (size_t)(t*2)*NE;
    const float2* __restrict__ ea2 = (const float2*)eattr + (size_t)t*NE;
    const int* __restrict__ pl = pool + (size_t)t*NE;
    float den=0.f, n0=0.f, n1=0.f;
    for (int j=js; j<je; j++){
      const int eid = pl[j];
      const int src = srcp[eid];
      const float2 ea = ea2[eid];
      const float4* xsp = (const float4*)(xall + (size_t)(c_xoff[st]+src)*8);
      float4 a0v = xsp[0], a1v = xsp[1];
      float xs[8] = {a0v.x,a0v.y,a0v.z,a0v.w,a1v.x,a1v.y,a1v.z,a1v.w};
      float acc = accd;
      float v0 = fmaf(ea.x, sP[140], fmaf(ea.y, sP[142], sP[144]+sP[146]));
      float v1 = fmaf(ea.x, sP[141], fmaf(ea.y, sP[143], sP[145]+sP[147]));
      #pragma unroll
      for (int f=0;f<8;f++){
        acc = fmaf(xs[f], r2[f], acc);
        v0  = fmaf(xs[f], sP[104+f], v0);
        v1  = fmaf(xs[f], sP[112+f], v1);
      }
      acc = fmaf(ea.x, t0, fmaf(ea.y, t1, acc));
      const float pe = __expf(acc * 0.08838834764831845f);
      den += pe; n0 = fmaf(pe, v0, n0); n1 = fmaf(pe, v1, n1);
    }
    const float inv = 1.0f/(den + 1e-16f);
    float s0 = fmaf(n0, inv, sP[148]);
    float s1 = fmaf(n1, inv, sP[149]);
    #pragma unroll
    for (int f=0;f<8;f++){ s0 = fmaf(xd[f], sP[120+f], s0); s1 = fmaf(xd[f], sP[128+f], s1); }
    const int base = c_aggoff[dt] + (i*c_cnt[dt] + c_slot[t])*N + n;
    g[(size_t)base*2+0]=s0; g[(size_t)base*2+1]=s1;
    #pragma unroll
    for (int h=0;h<64;h++){
      float z = fmaf(s0, wlb[h], fmaf(s1, wlb[64+h], wlb[128+h]));
      lmin = fminf(lmin,z); lmax = fmaxf(lmax,z);
    }
  }
  #pragma unroll
  for (int m=32;m>=1;m>>=1){
    lmin = fminf(lmin, __shfl_xor(lmin,m));
    lmax = fmaxf(lmax, __shfl_xor(lmax,m));
  }
  const int wv = tid>>6;
  if ((tid&63)==0){ smin[wv]=lmin; smax[wv]=lmax; }
  __syncthreads();
  if (tid==0){
    float mn = fminf(fminf(smin[0],smin[1]), fminf(smin[2],smin[3]));
    float mx = fmaxf(fmaxf(smax[0],smax[1]), fmaxf(smax[2],smax[3]));
    atomicMin(&mm[0], encf(mn));
    atomicMax(&mm[1], encf(mx));
  }
}

// ---- final: wave handles 32 rows; Wfc column resident in VGPRs, amortized ----
__global__ __launch_bounds__(256) void k_final(
    const float* __restrict__ g, const unsigned* __restrict__ mm,
    const float* __restrict__ Wl, const float* __restrict__ bl,
    const float* __restrict__ Wfc, const float* __restrict__ bfc,
    const float* __restrict__ Wl2, const float* __restrict__ bl2,
    float* __restrict__ out){
  const int bid = blockIdx.x;
  int nt, bo;
  if (bid < 188)       { nt=0; bo=0; }
  else if (bid < 2063) { nt=1; bo=188; }
  else if (bid < 3001) { nt=2; bo=2063; }
  else                 { nt=3; bo=3001; }
  const int w = threadIdx.x>>6, lane = threadIdx.x&63;
  const int R = c_aggrows[nt];
  const int r0 = (bid-bo)*128 + w*32;
  if (r0 >= R) return;  // wave-uniform, no barriers below
  const float wl0 = Wl[lane], wl1 = Wl[64+lane], blv = bl[lane];
  const float bfcv = bfc[nt*64+lane];
  const float wl20 = Wl2[lane], wl21 = Wl2[64+lane], bl2v = bl2[lane];
  float wfcr[64];
  const float* W = Wfc + (size_t)nt*4096;
  #pragma unroll
  for (int h=0;h<64;h++) wfcr[h] = W[h*64 + lane];
  const float zmin = decf(mm[0]), zmax = decf(mm[1]);
  const float rmin = 0.1f*eluf(zmin);
  const float rmax = 0.9f + 0.1f*eluf(zmax);
  const float s2 = 2.0f/(rmax - rmin + 1e-5f);
  const int nrows = min(32, R - r0);
  float gx=0.f, gy=0.f;
  if (lane < nrows){
    const float2 gv = ((const float2*)g)[c_aggoff[nt] + r0 + lane];
    gx = gv.x; gy = gv.y;
  }
  for (int r=0; r<nrows; r++){
    const float g0 = __uint_as_float(__builtin_amdgcn_readlane(__float_as_uint(gx), r));
    const float g1 = __uint_as_float(__builtin_amdgcn_readlane(__float_as_uint(gy), r));
    const float z = fmaf(g0, wl0, fmaf(g1, wl1, blv));
    const float nrm = fmaf(eluf(z) - rmin, s2, -1.0f);
    float acc = bfcv;
    #pragma unroll
    for (int h=0;h<64;h++){
      float nh = __uint_as_float(__builtin_amdgcn_readlane(__float_as_uint(nrm), h));
      acc = fmaf(nh, wfcr[h], acc);
    }
    float b = eluf(acc);
    float sgm = b;
    sgm += __shfl_xor(sgm,16);
    sgm += __shfl_xor(sgm,8);
    sgm += __shfl_xor(sgm,4);
    sgm += __shfl_xor(sgm,2);
    sgm += __shfl_xor(sgm,1);
    const float h0 = __uint_as_float(__builtin_amdgcn_readlane(__float_as_uint(sgm),0));
    const float h1 = __uint_as_float(__builtin_amdgcn_readlane(__float_as_uint(sgm),32));
    const float f = eluf(fmaf(h0, wl20, fmaf(h1, wl21, bl2v)));
    const size_t orow = (size_t)c_outoff[nt] + r0 + r;
    out[orow*64 + lane] = f;
    out[(orow + (size_t)R)*64 + lane] = f;
  }
}

extern "C" void kernel_launch(void* const* d_in, const int* in_sizes, int n_in,
                              void* d_out, int out_size, void* d_ws, size_t ws_size,
                              hipStream_t stream) {
  const float* xSB = (const float*)d_in[0];
  const float* cSB = (const float*)d_in[1];
  const float* xPQ = (const float*)d_in[2];
  const float* cPQ = (const float*)d_in[3];
  const float* xPV = (const float*)d_in[4];
  const float* cPV = (const float*)d_in[5];
  const float* xNB = (const float*)d_in[6];
  const float* cNB = (const float*)d_in[7];
  const int*   eidx = (const int*)d_in[8];
  const float* eattr= (const float*)d_in[9];
  const float* Wq = (const float*)d_in[10];
  const float* bq = (const float*)d_in[11];
  const float* Wk = (const float*)d_in[12];
  const float* bk = (const float*)d_in[13];
  const float* Wv = (const float*)d_in[14];
  const float* bv = (const float*)d_in[15];
  const float* We = (const float*)d_in[16];
  const float* be = (const float*)d_in[17];
  const float* Ws = (const float*)d_in[18];
  const float* bs = (const float*)d_in[19];
  const float* Wl = (const float*)d_in[20];
  const float* bl = (const float*)d_in[21];
  const float* Wfc= (const float*)d_in[22];
  const float* bfc= (const float*)d_in[23];
  const float* Wl2= (const float*)d_in[24];
  const float* bl2= (const float*)d_in[25];

  float* ws   = (float*)d_ws;
  float* xall   = ws + 0;              // 488000 f
  float* par    = ws + 488000;         // 4800 f
  int*   gstart = (int*)(ws + 492800); // 240015 i
  float* g      = ws + 732816;         // 960000 f
  int*   pool   = (int*)(ws + 1692816);// 2250000 i
  unsigned* mm  = (unsigned*)(ws + 3942816); // 2

  hipMemsetAsync(mm,   0xFF, 4, stream);  // encoded min identity
  hipMemsetAsync(mm+1, 0x00, 4, stream);  // encoded max identity

  k_build_x<<<(61000+255)/256, 256, 0, stream>>>(xSB,cSB,xPQ,cPQ,xPV,cPV,xNB,cNB, xall);
  k_params<<<30, 64, 0, stream>>>(Wq,bq,Wk,bk,Wv,bv,We,be,Ws,bs, par);
  k_csr<<<15, 1024, 0, stream>>>(eidx, gstart, pool);
  dim3 gg((30000+255)/256, 30);
  k_gather<<<gg, 256, 0, stream>>>(eidx, eattr, gstart, pool, xall, par, Wl, bl, g, mm);
  k_final<<<3751, 256, 0, stream>>>(g, mm, Wl, bl, Wfc, bfc, Wl2, bl2, (float*)d_out);
}